// Round 16
// baseline (1139.470 us; speedup 1.0000x reference)
//
#include <hip/hip_runtime.h>
#include <math.h>

// PNA GNN forward, MI355X. Round 16: k_post 32 nodes/block (512 thr).
// THEORY: phase B streams the full 850KB post B-panel per block from L2
// (2.66 GB/layer = ~77us) — the invisible floor that made all phase-A tweaks
// neutral. 8 waves x 1 N-tile x 2 M-tiles shares each B read across 32 rows:
// B traffic halves. Ghost rows (NN%32!=0) fully guarded (r14 lesson).

#define NN 50000
#define NE 200000
#define HD 128
#define NG 1000
#define EPSV 1e-5f
#define ALOGC 1.1330197327247628f

#define AP 1288    // a_lds row pitch (ushorts)
#define OPF 132    // o_f row pitch (floats)
#define ECAP2 1024
#define SCB 49

typedef __bf16 bf16x8 __attribute__((ext_vector_type(8)));
typedef float f32x4 __attribute__((ext_vector_type(4)));

__device__ __forceinline__ unsigned short f2bf(float f) {
    unsigned int u = __float_as_uint(f);
    unsigned int r = (u + 0x7FFFu + ((u >> 16) & 1u)) >> 16;
    return (unsigned short)r;
}
__device__ __forceinline__ float bf2f(unsigned short h) {
    return __uint_as_float((unsigned int)h << 16);
}

__global__ void k_fill(float* __restrict__ o, float v, int n) {
    int i = blockIdx.x * 256 + threadIdx.x;
    if (i < n) o[i] = v;
}

__global__ void k_zero(float* __restrict__ z, int n) {
    int i = blockIdx.x * 256 + threadIdx.x;
    if (i < n) z[i] = 0.f;
}

// ---------------- node encoder ----------------
__global__ __launch_bounds__(256) void k_encode_nodes(
    const int* __restrict__ x, const float* __restrict__ aemb, float* __restrict__ h) {
    __shared__ int xi[8][9];
    int nb = blockIdx.x * 8;
    int tid = threadIdx.x;
    if (tid < 72) xi[tid / 9][tid % 9] = x[nb * 9 + tid];
    __syncthreads();
    int node = tid >> 5, c4 = (tid & 31) * 4;
    float4 acc = make_float4(0.f, 0.f, 0.f, 0.f);
#pragma unroll
    for (int f = 0; f < 9; ++f) {
        float4 e = *(const float4*)(aemb + (size_t)(f * 64 + xi[node][f]) * HD + c4);
        acc.x += e.x; acc.y += e.y; acc.z += e.z; acc.w += e.w;
    }
    *(float4*)(h + (size_t)(nb + node) * HD + c4) = acc;
}

// ---------------- CSR build (parallel scan) ----------------
__global__ void k_count(const int* __restrict__ dst, int* __restrict__ cnt) {
    int e = blockIdx.x * 256 + threadIdx.x;
    if (e < NE) atomicAdd(&cnt[dst[e]], 1);
}

__global__ __launch_bounds__(1024) void k_scanA(const int* __restrict__ cnt,
                                                int* __restrict__ sc, int* __restrict__ tot) {
    __shared__ int buf[1024];
    int tid = threadIdx.x;
    int i = blockIdx.x * 1024 + tid;
    int v = (i < NN) ? cnt[i] : 0;
    buf[tid] = v;
    __syncthreads();
    for (int s = 1; s < 1024; s <<= 1) {
        int t = (tid >= s) ? buf[tid - s] : 0;
        __syncthreads();
        buf[tid] += t;
        __syncthreads();
    }
    if (i < NN) sc[i] = buf[tid];
    if (tid == 1023) tot[blockIdx.x] = buf[1023];
}

__global__ void k_scanB(const int* __restrict__ tot, int* __restrict__ offb) {
    if (threadIdx.x == 0) {
        int run = 0;
        for (int b = 0; b < SCB; ++b) { offb[b] = run; run += tot[b]; }
    }
}

__global__ __launch_bounds__(1024) void k_scanC(
    const int* __restrict__ cnt, const int* __restrict__ sc, const int* __restrict__ offb,
    int* __restrict__ rowptr, float* __restrict__ ampv, float* __restrict__ attv) {
    int i = blockIdx.x * 1024 + threadIdx.x;
    if (i == 0) rowptr[0] = 0;
    if (i < NN) {
        rowptr[i + 1] = offb[blockIdx.x] + sc[i];
        int v = cnt[i];
        float dg = (float)(v > 0 ? v : 1);
        float lg = logf(dg + 1.0f);
        ampv[i] = lg / ALOGC;
        attv[i] = ALOGC / lg;
    }
}

__global__ void k_scatter(const int* __restrict__ ei, const int* __restrict__ eai,
                          const int* __restrict__ rowptr,
                          int* __restrict__ fill, int* __restrict__ precs) {
    int e = blockIdx.x * 256 + threadIdx.x;
    if (e < NE) {
        int d = ei[NE + e];
        int pos = rowptr[d] + atomicAdd(&fill[d], 1);
        int cidx = eai[e * 3] | (eai[e * 3 + 1] << 3) | (eai[e * 3 + 2] << 6);
        precs[pos] = ei[e] | (cidx << 17);
    }
}

// ---------------- fold edge_W into pre_W chunk3 ----------------
__global__ void k_fold(const float* __restrict__ edge_W, const float* __restrict__ edge_b,
                       const float* __restrict__ pre_W, const float* __restrict__ pre_b,
                       float* __restrict__ cW, float* __restrict__ tb) {
    int l = blockIdx.y;
    int k = blockIdx.x;
    int tj = threadIdx.x;
    int t = tj >> 7, j = tj & 127;
    const float* pw = pre_W + ((size_t)(l * 2 + t) * 384 + 256) * 128 + j;
    if (k < 128) {
        const float* ew = edge_W + ((size_t)l * 128 + k) * 128;
        float acc = 0.f;
        for (int i = 0; i < 128; ++i) acc += ew[i] * pw[i * 128];
        cW[((size_t)l * 128 + k) * 256 + tj] = acc;
    } else {
        const float* eb = edge_b + l * 128;
        float acc = pre_b[(l * 2 + t) * 128 + j];
        for (int i = 0; i < 128; ++i) acc += eb[i] * pw[i * 128];
        tb[l * 256 + tj] = acc;
    }
}

// ---------------- combined bond table, direct from bemb ----------------
__global__ void k_bcomb2(const float* __restrict__ bemb, const float* __restrict__ cW,
                         unsigned short* __restrict__ bcomb) {
    int ci = blockIdx.x, l = blockIdx.y, tj = threadIdx.x;
    const float* s0 = bemb + (size_t)(0 * 8 + (ci & 7)) * 128;
    const float* s1 = bemb + (size_t)(1 * 8 + ((ci >> 3) & 7)) * 128;
    const float* s2 = bemb + (size_t)(2 * 8 + (ci >> 6)) * 128;
    const float* w = cW + (size_t)l * 128 * 256;
    float acc = 0.f;
    for (int i = 0; i < 128; ++i) acc += (s0[i] + s1[i] + s2[i]) * w[i * 256 + tj];
    bcomb[((size_t)l * 512 + ci) * 256 + tj] = f2bf(acc);
}

// ---------------- merged weight packing (hi/lo planes) ----------------
__device__ __forceinline__ void pack_body2(const float* __restrict__ W, int N, int NT,
                                           unsigned short* __restrict__ pkh,
                                           unsigned short* __restrict__ pkl,
                                           int blk, int lane) {
    int kstep = blk / NT, nt = blk - kstep * NT;
    int kb = kstep * 32 + (lane >> 4) * 8;
    int col = nt * 16 + (lane & 15);
    unsigned short th[8], tl[8];
#pragma unroll
    for (int i = 0; i < 8; ++i) {
        float w = W[(size_t)(kb + i) * N + col];
        unsigned short hh = f2bf(w);
        th[i] = hh;
        tl[i] = f2bf(w - bf2f(hh));
    }
    size_t base = ((size_t)blk * 64 + lane) * 8;
    *(uint4*)(pkh + base) = *(uint4*)th;
    *(uint4*)(pkl + base) = *(uint4*)tl;
}

__global__ __launch_bounds__(64) void k_packall(
    const float* __restrict__ post_W, const float* __restrict__ lin_W,
    const float* __restrict__ pre_W,
    unsigned short* __restrict__ pkPostHi, unsigned short* __restrict__ pkPostLo,
    unsigned short* __restrict__ pkLinHi, unsigned short* __restrict__ pkLinLo,
    unsigned short* __restrict__ pkPreHi, unsigned short* __restrict__ pkPreLo) {
    int b = blockIdx.x;
    int lane = threadIdx.x;
    if (b < 1248) {
        int l = b / 416, rem = b % 416;
        int t = rem / 208, blk = rem % 208;
        size_t off = ((size_t)l * 2 + t) * 106496;
        pack_body2(post_W + ((size_t)l * 2 + t) * 1664 * 64, 64, 4,
                   pkPostHi + off, pkPostLo + off, blk, lane);
    } else if (b < 1344) {
        int idx = b - 1248;
        int l = idx / 32, blk = idx % 32;
        pack_body2(lin_W + (size_t)l * 128 * 128, 128, 8,
                   pkLinHi + (size_t)l * 16384, pkLinLo + (size_t)l * 16384, blk, lane);
    } else {
        int idx = b - 1344;
        int l = idx / 128, bb = idx % 128;
        const float* preW = pre_W + (size_t)l * 2 * 384 * 128;
        unsigned short* phi = pkPreHi + (size_t)l * 65536;
        unsigned short* plo = pkPreLo + (size_t)l * 65536;
        int kstep = bb >> 5, nt = bb & 31;
        int q = lane >> 4, nc = lane & 15;
        int col = nt * 16 + nc;
        int t = (col >> 7) & 1;
        int jcol = col & 127;
        int fbase = (col < 256) ? 0 : 128;
        unsigned short hi[8], lo[8];
#pragma unroll
        for (int i = 0; i < 8; ++i) {
            int k = kstep * 32 + q * 8 + i;
            float w = preW[((size_t)t * 384 + fbase + k) * 128 + jcol];
            unsigned short h16 = f2bf(w);
            hi[i] = h16;
            lo[i] = f2bf(w - bf2f(h16));
        }
        size_t base = ((size_t)bb * 64 + lane) * 8;
        *(uint4*)(phi + base) = *(uint4*)hi;
        *(uint4*)(plo + base) = *(uint4*)lo;
    }
}

// ---------------- pre-transform MFMA body: 2 M-tiles share B loads ----------
__device__ __forceinline__ void pre_mfma_body2(
    const unsigned short* __restrict__ ah, const unsigned short* __restrict__ al,
    const unsigned short* __restrict__ phi, const unsigned short* __restrict__ plo,
    const float* __restrict__ tb, int n0, int tid,
    unsigned short* __restrict__ hzd, unsigned short* __restrict__ hzs) {
    int lane = tid & 63, w = tid >> 6;
    int q = lane >> 4, nc = lane & 15;
    f32x4 acc0[8], acc1[8];
#pragma unroll
    for (int j = 0; j < 8; ++j) {
        acc0[j] = (f32x4){0.f, 0.f, 0.f, 0.f};
        acc1[j] = (f32x4){0.f, 0.f, 0.f, 0.f};
    }
#pragma unroll
    for (int kk = 0; kk < 4; ++kk) {
        bf16x8 Ahi0 = *(const bf16x8*)(ah + nc * 136 + kk * 32 + q * 8);
        bf16x8 Alo0 = *(const bf16x8*)(al + nc * 136 + kk * 32 + q * 8);
        bf16x8 Ahi1 = *(const bf16x8*)(ah + (16 + nc) * 136 + kk * 32 + q * 8);
        bf16x8 Alo1 = *(const bf16x8*)(al + (16 + nc) * 136 + kk * 32 + q * 8);
#pragma unroll
        for (int j = 0; j < 8; ++j) {
            int nt = w * 8 + j;
            size_t base = ((size_t)(kk * 32 + nt) * 64 + lane) * 8;
            bf16x8 Bhi = *(const bf16x8*)(phi + base);
            bf16x8 Blo = *(const bf16x8*)(plo + base);
            acc0[j] = __builtin_amdgcn_mfma_f32_16x16x32_bf16(Ahi0, Bhi, acc0[j], 0, 0, 0);
            acc0[j] = __builtin_amdgcn_mfma_f32_16x16x32_bf16(Ahi0, Blo, acc0[j], 0, 0, 0);
            acc0[j] = __builtin_amdgcn_mfma_f32_16x16x32_bf16(Alo0, Bhi, acc0[j], 0, 0, 0);
            acc1[j] = __builtin_amdgcn_mfma_f32_16x16x32_bf16(Ahi1, Bhi, acc1[j], 0, 0, 0);
            acc1[j] = __builtin_amdgcn_mfma_f32_16x16x32_bf16(Ahi1, Blo, acc1[j], 0, 0, 0);
            acc1[j] = __builtin_amdgcn_mfma_f32_16x16x32_bf16(Alo1, Bhi, acc1[j], 0, 0, 0);
        }
    }
#pragma unroll
    for (int j = 0; j < 8; ++j) {
        int col = (w * 8 + j) * 16 + nc;
        float bias = (col < 256) ? tb[col] : 0.f;
#pragma unroll
        for (int reg = 0; reg < 4; ++reg) {
            int r0 = n0 + q * 4 + reg;
            int r1 = r0 + 16;
            if (col < 256) {
                if (r0 < NN) hzd[(size_t)r0 * 256 + col] = f2bf(acc0[j][reg] + bias);
                if (r1 < NN) hzd[(size_t)r1 * 256 + col] = f2bf(acc1[j][reg] + bias);
            } else {
                if (r0 < NN) hzs[(size_t)r0 * 256 + (col - 256)] = f2bf(acc0[j][reg]);
                if (r1 < NN) hzs[(size_t)r1 * 256 + (col - 256)] = f2bf(acc1[j][reg]);
            }
        }
    }
}

// ---------------- node pre-transform via MFMA (layer 0), 32 nodes/block ------
__global__ __launch_bounds__(256) void k_pre_m(
    const float* __restrict__ h,
    const unsigned short* __restrict__ phi, const unsigned short* __restrict__ plo,
    const float* __restrict__ tb,
    unsigned short* __restrict__ hzd, unsigned short* __restrict__ hzs) {
    __shared__ __align__(16) unsigned short ah[32 * 136];
    __shared__ __align__(16) unsigned short al[32 * 136];
    int n0 = blockIdx.x * 32;
    int tid = threadIdx.x;
    for (int half = 0; half < 2; ++half) {
        int node = (tid >> 4) + half * 16, cg = (tid & 15) * 8;
        int n = n0 + node;
        unsigned short hh[8] = {0, 0, 0, 0, 0, 0, 0, 0};
        unsigned short ll[8] = {0, 0, 0, 0, 0, 0, 0, 0};
        if (n < NN) {
            const float* hs = h + (size_t)n * HD + cg;
            float4 v0 = *(const float4*)(hs);
            float4 v1 = *(const float4*)(hs + 4);
            float vv[8] = {v0.x, v0.y, v0.z, v0.w, v1.x, v1.y, v1.z, v1.w};
#pragma unroll
            for (int i = 0; i < 8; ++i) {
                hh[i] = f2bf(vv[i]);
                ll[i] = f2bf(vv[i] - bf2f(hh[i]));
            }
        }
        *(uint4*)(ah + node * 136 + cg) = *(uint4*)hh;
        *(uint4*)(al + node * 136 + cg) = *(uint4*)ll;
    }
    __syncthreads();
    pre_mfma_body2(ah, al, phi, plo, tb, n0, tid, hzd, hzs);
}

// ---------------- fused BN+ReLU+pre-transform (layers 1,2), 32 nodes/block ----
__global__ __launch_bounds__(256) void k_bnpre(
    const float* __restrict__ o2, const float* __restrict__ stats,
    const float* __restrict__ g, const float* __restrict__ b,
    const unsigned short* __restrict__ phi, const unsigned short* __restrict__ plo,
    const float* __restrict__ tb,
    float* __restrict__ h, unsigned short* __restrict__ hzd, unsigned short* __restrict__ hzs) {
    __shared__ __align__(16) unsigned short ah[32 * 136];
    __shared__ __align__(16) unsigned short al[32 * 136];
    int n0 = blockIdx.x * 32;
    int tid = threadIdx.x;
    for (int half = 0; half < 2; ++half) {
        int node = (tid >> 4) + half * 16, cg = (tid & 15) * 8;
        int n = n0 + node;
        unsigned short hh[8] = {0, 0, 0, 0, 0, 0, 0, 0};
        unsigned short ll[8] = {0, 0, 0, 0, 0, 0, 0, 0};
        if (n < NN) {
            const float* os = o2 + (size_t)n * HD + cg;
            float4 v0 = *(const float4*)(os);
            float4 v1 = *(const float4*)(os + 4);
            float vv[8] = {v0.x, v0.y, v0.z, v0.w, v1.x, v1.y, v1.z, v1.w};
            float ou[8];
#pragma unroll
            for (int i = 0; i < 8; ++i) {
                int c = cg + i;
                float mu = stats[c] * (1.f / NN);
                float var = stats[128 + c] * (1.f / NN) - mu * mu;
                float val = (vv[i] - mu) * rsqrtf(var + EPSV) * g[c] + b[c];
                val = fmaxf(val, 0.f);
                ou[i] = val;
                hh[i] = f2bf(val);
                ll[i] = f2bf(val - bf2f(hh[i]));
            }
            float* hd = h + (size_t)n * HD + cg;
            *(float4*)(hd) = make_float4(ou[0], ou[1], ou[2], ou[3]);
            *(float4*)(hd + 4) = make_float4(ou[4], ou[5], ou[6], ou[7]);
        }
        *(uint4*)(ah + node * 136 + cg) = *(uint4*)hh;
        *(uint4*)(al + node * 136 + cg) = *(uint4*)ll;
    }
    __syncthreads();
    pre_mfma_body2(ah, al, phi, plo, tb, n0, tid, hzd, hzs);
}

// ---------------- fused: message + agg + MFMA post + lin, 32 nodes, 512 thr ----
__global__ __launch_bounds__(512) void k_post(
    const float* __restrict__ h,
    const unsigned short* __restrict__ hzd, const unsigned short* __restrict__ hzs,
    const int* __restrict__ rowptr, const int* __restrict__ precs,
    const unsigned short* __restrict__ bcomb,
    const float* __restrict__ ampv, const float* __restrict__ attv,
    const unsigned short* __restrict__ pkPostHi, const unsigned short* __restrict__ pkPostLo,
    const float* __restrict__ postb,
    const unsigned short* __restrict__ pkLinHi, const unsigned short* __restrict__ pkLinLo,
    const float* __restrict__ linb,
    float* __restrict__ o2, float* __restrict__ stats) {
    __shared__ __align__(16) unsigned short a_lds[32 * AP];   // 82432 B
    __shared__ __align__(16) float o_f[32 * OPF];             // 16896 B
    __shared__ int es[ECAP2];                                 // 4096 B
    __shared__ float s_amp[32], s_att[32];
    int n0 = blockIdx.x * 32;
    int tid = threadIdx.x;
    int nEnd = (n0 + 32 < NN) ? (n0 + 32) : NN;

    int pbase = rowptr[n0];
    int ecount = rowptr[nEnd] - pbase;
    for (int i = tid; i < ecount && i < ECAP2; i += 512) es[i] = precs[pbase + i];
    {   // stage h tile -> bf16, duplicated into both t-sections (ghost rows = 0)
        int node = tid >> 4, cg = (tid & 15) * 8;
        int n = n0 + node;
        unsigned short bb[8] = {0, 0, 0, 0, 0, 0, 0, 0};
        if (n < NN) {
            const float* hs = h + (size_t)n * HD + cg;
            float4 v0 = *(const float4*)(hs);
            float4 v1 = *(const float4*)(hs + 4);
            bb[0] = f2bf(v0.x); bb[1] = f2bf(v0.y); bb[2] = f2bf(v0.z); bb[3] = f2bf(v0.w);
            bb[4] = f2bf(v1.x); bb[5] = f2bf(v1.y); bb[6] = f2bf(v1.z); bb[7] = f2bf(v1.w);
        }
        unsigned short* d0 = a_lds + node * AP + cg;
        unsigned short* d1 = d0 + 640;
#pragma unroll
        for (int i = 0; i < 8; ++i) { d0[i] = bb[i]; d1[i] = bb[i]; }
    }
    if (tid < 32) {
        int n = n0 + tid;
        s_amp[tid] = (n < NN) ? ampv[n] : 1.f;
        s_att[tid] = (n < NN) ? attv[n] : 1.f;
    }
    __syncthreads();

    // ---- phase A: 8 waves x 4 nodes, 2-node interleave, bf16 gathers ----
    {
        int wv = tid >> 6, lane = tid & 63;
        int cc = lane * 4;
        int tt = cc >> 7, jj = cc & 127;
        bool incap = (ecount <= ECAP2);
        const float4 Z4 = make_float4(0.f, 0.f, 0.f, 0.f);
        const float4 BIG = make_float4(3.4e38f, 3.4e38f, 3.4e38f, 3.4e38f);
        const float4 NBIG = make_float4(-3.4e38f, -3.4e38f, -3.4e38f, -3.4e38f);

#define EDGE_ACC(P, S1, S2, MN, MX)                                                       \
        {                                                                                 \
            int rec = incap ? es[(P) - pbase] : precs[(P)];                               \
            int sp = rec & 131071;                                                        \
            int ci = rec >> 17;                                                           \
            uint2 uv = *(const uint2*)(hzs + (size_t)sp * 256 + cc);                      \
            uint2 ub = *(const uint2*)(bcomb + (size_t)ci * 256 + cc);                    \
            float wx = __uint_as_float(uv.x << 16) + __uint_as_float(ub.x << 16);         \
            float wy = __uint_as_float(uv.x & 0xffff0000u) + __uint_as_float(ub.x & 0xffff0000u); \
            float wz = __uint_as_float(uv.y << 16) + __uint_as_float(ub.y << 16);         \
            float ww = __uint_as_float(uv.y & 0xffff0000u) + __uint_as_float(ub.y & 0xffff0000u); \
            S1.x += wx; S1.y += wy; S1.z += wz; S1.w += ww;                               \
            S2.x += wx * wx; S2.y += wy * wy; S2.z += wz * wz; S2.w += ww * ww;           \
            MN.x = fminf(MN.x, wx); MN.y = fminf(MN.y, wy);                               \
            MN.z = fminf(MN.z, wz); MN.w = fminf(MN.w, ww);                               \
            MX.x = fmaxf(MX.x, wx); MX.y = fmaxf(MX.y, wy);                               \
            MX.z = fmaxf(MX.z, wz); MX.w = fmaxf(MX.w, ww);                               \
        }

        auto fin = [&](int r, int cnt, float4 hd, float4 s1, float4 s2, float4 mn, float4 mx) {
            float inv = 1.f / (float)(cnt > 0 ? cnt : 1);
            float4 mw, stdv, mean;
            mw.x = s1.x * inv; mw.y = s1.y * inv; mw.z = s1.z * inv; mw.w = s1.w * inv;
            stdv.x = sqrtf(fmaxf(s2.x * inv - mw.x * mw.x, 0.f) + EPSV);
            stdv.y = sqrtf(fmaxf(s2.y * inv - mw.y * mw.y, 0.f) + EPSV);
            stdv.z = sqrtf(fmaxf(s2.z * inv - mw.z * mw.z, 0.f) + EPSV);
            stdv.w = sqrtf(fmaxf(s2.w * inv - mw.w * mw.w, 0.f) + EPSV);
            if (cnt > 0) {
                mean.x = hd.x + mw.x; mean.y = hd.y + mw.y;
                mean.z = hd.z + mw.z; mean.w = hd.w + mw.w;
                mn.x += hd.x; mn.y += hd.y; mn.z += hd.z; mn.w += hd.w;
                mx.x += hd.x; mx.y += hd.y; mx.z += hd.z; mx.w += hd.w;
            } else {
                mean = Z4; mn = Z4; mx = Z4;
            }
            unsigned short* d = a_lds + r * AP + tt * 640 + 128 + jj;
            d[0] = f2bf(mean.x); d[1] = f2bf(mean.y); d[2] = f2bf(mean.z); d[3] = f2bf(mean.w);
            d += 128; d[0] = f2bf(mn.x); d[1] = f2bf(mn.y); d[2] = f2bf(mn.z); d[3] = f2bf(mn.w);
            d += 128; d[0] = f2bf(mx.x); d[1] = f2bf(mx.y); d[2] = f2bf(mx.z); d[3] = f2bf(mx.w);
            d += 128; d[0] = f2bf(stdv.x); d[1] = f2bf(stdv.y); d[2] = f2bf(stdv.z); d[3] = f2bf(stdv.w);
        };

        for (int i = 0; i < 2; ++i) {
            int ra = wv * 4 + i * 2;
            int rb = ra + 1;
            int na = n0 + ra, nb = n0 + rb;
            int pa0 = 0, pa1 = 0, pb0 = 0, pb1 = 0;
            float4 hda = Z4, hdb = Z4;
            if (na < NN) {
                pa0 = rowptr[na]; pa1 = rowptr[na + 1];
                uint2 uda = *(const uint2*)(hzd + (size_t)na * 256 + cc);
                hda.x = __uint_as_float(uda.x << 16); hda.y = __uint_as_float(uda.x & 0xffff0000u);
                hda.z = __uint_as_float(uda.y << 16); hda.w = __uint_as_float(uda.y & 0xffff0000u);
            }
            if (nb < NN) {
                pb0 = rowptr[nb]; pb1 = rowptr[nb + 1];
                uint2 udb = *(const uint2*)(hzd + (size_t)nb * 256 + cc);
                hdb.x = __uint_as_float(udb.x << 16); hdb.y = __uint_as_float(udb.x & 0xffff0000u);
                hdb.z = __uint_as_float(udb.y << 16); hdb.w = __uint_as_float(udb.y & 0xffff0000u);
            }
            float4 s1a = Z4, s2a = Z4, mna = BIG, mxa = NBIG;
            float4 s1b = Z4, s2b = Z4, mnb = BIG, mxb = NBIG;
            int da = pa1 - pa0, db = pb1 - pb0;
            int mc = (da < db) ? da : db;
            for (int k = 0; k < mc; ++k) {
                EDGE_ACC(pa0 + k, s1a, s2a, mna, mxa)
                EDGE_ACC(pb0 + k, s1b, s2b, mnb, mxb)
            }
            for (int k = mc; k < da; ++k) EDGE_ACC(pa0 + k, s1a, s2a, mna, mxa)
            for (int k = mc; k < db; ++k) EDGE_ACC(pb0 + k, s1b, s2b, mnb, mxb)
            fin(ra, da, hda, s1a, s2a, mna, mxa);
            fin(rb, db, hdb, s1b, s2b, mnb, mxb);
        }
#undef EDGE_ACC
    }
    __syncthreads();

    // ---- phase B: 8 waves x 1 N-tile x 2 M-tiles (B read once per block) ----
    {
        int lane = tid & 63;
        int w = tid >> 6;          // nt 0..7
        int t = w >> 2;            // 0..1
        int ntIn = w & 3;          // 0..3
        int q = lane >> 4, nc = lane & 15;
        const unsigned short* arow0 = a_lds + (size_t)nc * AP + t * 640 + q * 8;
        const unsigned short* arow1 = a_lds + (size_t)(16 + nc) * AP + t * 640 + q * 8;
        size_t toff = (size_t)t * 106496;
        const unsigned short* pkh = pkPostHi + toff;
        const unsigned short* pkl = pkPostLo + toff;
        f32x4 P0 = {0.f, 0.f, 0.f, 0.f}, P1 = {0.f, 0.f, 0.f, 0.f};
        f32x4 A0 = {0.f, 0.f, 0.f, 0.f}, A1 = {0.f, 0.f, 0.f, 0.f};
        f32x4 T0 = {0.f, 0.f, 0.f, 0.f}, T1 = {0.f, 0.f, 0.f, 0.f};
        for (int kk = 0; kk < 20; ++kk) {
            bf16x8 af0 = *(const bf16x8*)(arow0 + kk * 32);
            bf16x8 af1 = *(const bf16x8*)(arow1 + kk * 32);
            size_t ib = ((size_t)(kk * 4 + ntIn) * 64 + lane) * 8;
            bf16x8 Bh = *(const bf16x8*)(pkh + ib);
            bf16x8 Bl = *(const bf16x8*)(pkl + ib);
            P0 = __builtin_amdgcn_mfma_f32_16x16x32_bf16(af0, Bh, P0, 0, 0, 0);
            P0 = __builtin_amdgcn_mfma_f32_16x16x32_bf16(af0, Bl, P0, 0, 0, 0);
            P1 = __builtin_amdgcn_mfma_f32_16x16x32_bf16(af1, Bh, P1, 0, 0, 0);
            P1 = __builtin_amdgcn_mfma_f32_16x16x32_bf16(af1, Bl, P1, 0, 0, 0);
            if (kk >= 4) {
                size_t ia = ((size_t)((kk + 16) * 4 + ntIn) * 64 + lane) * 8;
                bf16x8 Ah = *(const bf16x8*)(pkh + ia);
                bf16x8 Al = *(const bf16x8*)(pkl + ia);
                A0 = __builtin_amdgcn_mfma_f32_16x16x32_bf16(af0, Ah, A0, 0, 0, 0);
                A0 = __builtin_amdgcn_mfma_f32_16x16x32_bf16(af0, Al, A0, 0, 0, 0);
                A1 = __builtin_amdgcn_mfma_f32_16x16x32_bf16(af1, Ah, A1, 0, 0, 0);
                A1 = __builtin_amdgcn_mfma_f32_16x16x32_bf16(af1, Al, A1, 0, 0, 0);
                size_t it = ((size_t)((kk + 32) * 4 + ntIn) * 64 + lane) * 8;
                bf16x8 Th = *(const bf16x8*)(pkh + it);
                bf16x8 Tl = *(const bf16x8*)(pkl + it);
                T0 = __builtin_amdgcn_mfma_f32_16x16x32_bf16(af0, Th, T0, 0, 0, 0);
                T0 = __builtin_amdgcn_mfma_f32_16x16x32_bf16(af0, Tl, T0, 0, 0, 0);
                T1 = __builtin_amdgcn_mfma_f32_16x16x32_bf16(af1, Th, T1, 0, 0, 0);
                T1 = __builtin_amdgcn_mfma_f32_16x16x32_bf16(af1, Tl, T1, 0, 0, 0);
            }
        }
        int col = t * 64 + ntIn * 16 + nc;
        float pbia = postb[col];
#pragma unroll
        for (int m = 0; m < 2; ++m) {
            f32x4 P = m ? P1 : P0;
            f32x4 A = m ? A1 : A0;
            f32x4 T = m ? T1 : T0;
#pragma unroll
            for (int reg = 0; reg < 4; ++reg) {
                int row = m * 16 + q * 4 + reg;
                o_f[row * OPF + col] = P[reg] + s_amp[row] * A[reg] + s_att[row] * T[reg] + pbia;
            }
        }
    }
    __syncthreads();

    // ---- lin: 8 waves x 1 N-tile x 2 M-tiles, A hi/lo on the fly ----
    {
        int lane = tid & 63;
        int w = tid >> 6;          // ntL 0..7
        int q = lane >> 4, nc = lane & 15;
        const float* arow0 = o_f + (size_t)nc * OPF + q * 8;
        const float* arow1 = o_f + (size_t)(16 + nc) * OPF + q * 8;
        f32x4 L0 = {0.f, 0.f, 0.f, 0.f}, L1 = {0.f, 0.f, 0.f, 0.f};
#pragma unroll
        for (int kk = 0; kk < 4; ++kk) {
            float4 a0 = *(const float4*)(arow0 + kk * 32);
            float4 a1 = *(const float4*)(arow0 + kk * 32 + 4);
            float4 b0 = *(const float4*)(arow1 + kk * 32);
            float4 b1 = *(const float4*)(arow1 + kk * 32 + 4);
            float v0[8] = {a0.x, a0.y, a0.z, a0.w, a1.x, a1.y, a1.z, a1.w};
            float v1[8] = {b0.x, b0.y, b0.z, b0.w, b1.x, b1.y, b1.z, b1.w};
            unsigned short h0[8], l0[8], h1[8], l1[8];
#pragma unroll
            for (int i = 0; i < 8; ++i) {
                h0[i] = f2bf(v0[i]); l0[i] = f2bf(v0[i] - bf2f(h0[i]));
                h1[i] = f2bf(v1[i]); l1[i] = f2bf(v1[i] - bf2f(h1[i]));
            }
            bf16x8 Ahi0 = *(const bf16x8*)h0;
            bf16x8 Alo0 = *(const bf16x8*)l0;
            bf16x8 Ahi1 = *(const bf16x8*)h1;
            bf16x8 Alo1 = *(const bf16x8*)l1;
            size_t ib = ((size_t)(kk * 8 + w) * 64 + lane) * 8;
            bf16x8 Bh = *(const bf16x8*)(pkLinHi + ib);
            bf16x8 Bl = *(const bf16x8*)(pkLinLo + ib);
            L0 = __builtin_amdgcn_mfma_f32_16x16x32_bf16(Ahi0, Bh, L0, 0, 0, 0);
            L0 = __builtin_amdgcn_mfma_f32_16x16x32_bf16(Alo0, Bh, L0, 0, 0, 0);
            L0 = __builtin_amdgcn_mfma_f32_16x16x32_bf16(Ahi0, Bl, L0, 0, 0, 0);
            L1 = __builtin_amdgcn_mfma_f32_16x16x32_bf16(Ahi1, Bh, L1, 0, 0, 0);
            L1 = __builtin_amdgcn_mfma_f32_16x16x32_bf16(Alo1, Bh, L1, 0, 0, 0);
            L1 = __builtin_amdgcn_mfma_f32_16x16x32_bf16(Ahi1, Bl, L1, 0, 0, 0);
        }
        int col = w * 16 + nc;
        float lb = linb[col];
        float ps = 0.f, pss = 0.f;
#pragma unroll
        for (int m = 0; m < 2; ++m) {
            f32x4 L = m ? L1 : L0;
#pragma unroll
            for (int reg = 0; reg < 4; ++reg) {
                int row = m * 16 + q * 4 + reg;
                int gn = n0 + row;
                float v = L[reg] + lb;
                if (gn < NN) {
                    o2[(size_t)gn * HD + col] = v;
                    ps += v; pss += v * v;
                }
            }
        }
        ps += __shfl_down(ps, 16); ps += __shfl_down(ps, 32);
        pss += __shfl_down(pss, 16); pss += __shfl_down(pss, 32);
        if (q == 0) {
            atomicAdd(&stats[col], ps);
            atomicAdd(&stats[128 + col], pss);
        }
    }
}

// ---------------- graph pooling with fused final BN+ReLU ----------------
__global__ void k_pool(const float* __restrict__ o2, const float* __restrict__ stats,
                       const float* __restrict__ g, const float* __restrict__ b,
                       const int* __restrict__ batch, float* __restrict__ g0) {
    int c = threadIdx.x;
    float mu = stats[c] * (1.f / NN);
    float var = stats[128 + c] * (1.f / NN) - mu * mu;
    float rs = rsqrtf(var + EPSV) * g[c];
    float bb = b[c];
    int nbase = blockIdx.x * 64;
    float run = 0.f; int cur = -1;
    for (int i = 0; i < 64; ++i) {
        int n = nbase + i;
        if (n >= NN) break;
        int bi = batch[n];
        if (bi != cur) {
            if (cur >= 0) atomicAdd(&g0[(size_t)cur * HD + c], run);
            cur = bi; run = 0.f;
        }
        run += fmaxf((o2[(size_t)n * HD + c] - mu) * rs + bb, 0.f);
    }
    if (cur >= 0) atomicAdd(&g0[(size_t)cur * HD + c], run);
}

// ---------------- head ----------------
__global__ void k_head_gemm(const float* __restrict__ x, const float* __restrict__ W,
                            const float* __restrict__ b, float* __restrict__ y,
                            float* __restrict__ stats, int K, int Kout) {
    int row = blockIdx.x;
    int col = threadIdx.x;
    if (col >= Kout) return;
    float acc = b[col];
    for (int k = 0; k < K; k += 4) {
        float4 xv = *(const float4*)(x + (size_t)row * K + k);
        acc += xv.x * W[(k + 0) * Kout + col] + xv.y * W[(k + 1) * Kout + col]
             + xv.z * W[(k + 2) * Kout + col] + xv.w * W[(k + 3) * Kout + col];
    }
    y[(size_t)row * Kout + col] = acc;
    if (stats) {
        atomicAdd(&stats[col], acc);
        atomicAdd(&stats[Kout + col], acc * acc);
    }
}

__global__ __launch_bounds__(128) void k_head_fused(
    const float* __restrict__ y_in, const float* __restrict__ stats_in,
    const float* __restrict__ g, const float* __restrict__ b,
    const float* __restrict__ W, const float* __restrict__ bias,
    float* __restrict__ y_out, float* __restrict__ stats_out, int Kin, int Kout) {
    __shared__ float row[128];
    int r = blockIdx.x, tid = threadIdx.x;
    if (tid < Kin) {
        float mu = stats_in[tid] * (1.f / NG);
        float var = stats_in[Kin + tid] * (1.f / NG) - mu * mu;
        float v = (y_in[(size_t)r * Kin + tid] - mu) * rsqrtf(var + EPSV) * g[tid] + b[tid];
        row[tid] = fmaxf(v, 0.f);
    }
    __syncthreads();
    if (tid < Kout) {
        float acc = bias[tid];
        for (int k = 0; k < Kin; ++k) acc += row[k] * W[(size_t)k * Kout + tid];
        y_out[(size_t)r * Kout + tid] = acc;
        if (stats_out) {
            atomicAdd(&stats_out[tid], acc);
            atomicAdd(&stats_out[Kout + tid], acc * acc);
        }
    }
}

extern "C" void kernel_launch(void* const* d_in, const int* in_sizes, int n_in,
                              void* d_out, int out_size, void* d_ws, size_t ws_size,
                              hipStream_t stream) {
    const int*   x        = (const int*)  d_in[0];
    const int*   ei       = (const int*)  d_in[1];
    const int*   batch    = (const int*)  d_in[2];
    const int*   eai      = (const int*)  d_in[3];
    const float* atom_emb = (const float*)d_in[4];
    const float* bond_emb = (const float*)d_in[5];
    const float* edge_W   = (const float*)d_in[6];
    const float* edge_b   = (const float*)d_in[7];
    const float* pre_W    = (const float*)d_in[8];
    const float* pre_b    = (const float*)d_in[9];
    const float* post_W   = (const float*)d_in[10];
    const float* post_b   = (const float*)d_in[11];
    const float* lin_W    = (const float*)d_in[12];
    const float* lin_b    = (const float*)d_in[13];
    const float* bn_g     = (const float*)d_in[14];
    const float* bn_b     = (const float*)d_in[15];
    const float* mlp_W    = (const float*)d_in[16];
    const float* mlp_b    = (const float*)d_in[17];
    const float* mlp_g    = (const float*)d_in[18];
    const float* mlp_be   = (const float*)d_in[19];
    const float* hW1 = (const float*)d_in[20]; const float* hb1  = (const float*)d_in[21];
    const float* hg1 = (const float*)d_in[22]; const float* hbe1 = (const float*)d_in[23];
    const float* hW2 = (const float*)d_in[24]; const float* hb2  = (const float*)d_in[25];
    const float* hg2 = (const float*)d_in[26]; const float* hbe2 = (const float*)d_in[27];
    const float* hW3 = (const float*)d_in[28]; const float* hb3  = (const float*)d_in[29];
    float* out = (float*)d_out;
    (void)n_in; (void)in_sizes;

    char* p = (char*)d_ws;
    size_t off = 0;
    auto alloc = [&](size_t bytes) -> char* {
        char* r = p + off;
        off += (bytes + 255) & ~(size_t)255;
        return r;
    };
    float* h     = (float*)alloc((size_t)NN * HD * 4);
    float* o2    = (float*)alloc((size_t)NN * HD * 4);
    unsigned short* hzd = (unsigned short*)alloc((size_t)NN * 256 * 2);
    unsigned short* hzs = (unsigned short*)alloc((size_t)NN * 256 * 2);
    float* ampv  = (float*)alloc((size_t)NN * 4);
    float* attv  = (float*)alloc((size_t)NN * 4);
    int*   rowptr= (int*)  alloc((size_t)(NN + 1) * 4);
    int*   precs = (int*)  alloc((size_t)NE * 4);
    int*   sc    = (int*)  alloc((size_t)NN * 4);
    int*   stot  = (int*)  alloc((size_t)SCB * 4);
    int*   soff  = (int*)  alloc((size_t)SCB * 4);
    float* cW    = (float*)alloc((size_t)3 * 128 * 256 * 4);
    float* tbb   = (float*)alloc((size_t)3 * 256 * 4);
    unsigned short* bcomb = (unsigned short*)alloc((size_t)3 * 512 * 256 * 2);
    unsigned short* pkPostHi = (unsigned short*)alloc((size_t)3 * 2 * 106496 * 2);
    unsigned short* pkPostLo = (unsigned short*)alloc((size_t)3 * 2 * 106496 * 2);
    unsigned short* pkLinHi  = (unsigned short*)alloc((size_t)3 * 16384 * 2);
    unsigned short* pkLinLo  = (unsigned short*)alloc((size_t)3 * 16384 * 2);
    unsigned short* pkPreHi  = (unsigned short*)alloc((size_t)3 * 65536 * 2);
    unsigned short* pkPreLo  = (unsigned short*)alloc((size_t)3 * 65536 * 2);
    float* gA    = (float*)alloc((size_t)NG * HD * 4);
    float* gB    = (float*)alloc((size_t)NG * HD * 4);
    char* z0 = p + off;   // ---- zero-init region ----
    int*   cnt   = (int*)  alloc((size_t)NN * 4);
    int*   fill  = (int*)  alloc((size_t)NN * 4);
    float* stats = (float*)alloc((size_t)3 * 256 * 4);
    float* hstats= (float*)alloc((size_t)4 * 256 * 4);
    float* g0    = (float*)alloc((size_t)NG * HD * 4);
    size_t zwords = (size_t)((p + off) - z0) / 4;

    if (off > ws_size) {
        k_fill<<<(out_size + 255) / 256, 256, 0, stream>>>(out, (float)ws_size, out_size);
        return;
    }

    k_zero<<<(int)((zwords + 255) / 256), 256, 0, stream>>>((float*)z0, (int)zwords);
    k_encode_nodes<<<NN / 8, 256, 0, stream>>>(x, atom_emb, h);
    k_count<<<(NE + 255) / 256, 256, 0, stream>>>(ei + NE, cnt);
    k_scanA<<<SCB, 1024, 0, stream>>>(cnt, sc, stot);
    k_scanB<<<1, 64, 0, stream>>>(stot, soff);
    k_scanC<<<SCB, 1024, 0, stream>>>(cnt, sc, soff, rowptr, ampv, attv);
    k_scatter<<<(NE + 255) / 256, 256, 0, stream>>>(ei, eai, rowptr, fill, precs);
    k_fold<<<dim3(129, 3), 256, 0, stream>>>(edge_W, edge_b, pre_W, pre_b, cW, tbb);
    k_bcomb2<<<dim3(512, 3), 256, 0, stream>>>(bond_emb, cW, bcomb);
    k_packall<<<1728, 64, 0, stream>>>(post_W, lin_W, pre_W,
        pkPostHi, pkPostLo, pkLinHi, pkLinLo, pkPreHi, pkPreLo);

    int preBlocks = (NN + 31) / 32;
    for (int l = 0; l < 3; ++l) {
        if (l == 0) {
            k_pre_m<<<preBlocks, 256, 0, stream>>>(h, pkPreHi, pkPreLo, tbb, hzd, hzs);
        } else {
            k_bnpre<<<preBlocks, 256, 0, stream>>>(o2, stats + (l - 1) * 256,
                bn_g + (l - 1) * 128, bn_b + (l - 1) * 128,
                pkPreHi + (size_t)l * 65536, pkPreLo + (size_t)l * 65536,
                tbb + l * 256, h, hzd, hzs);
        }
        k_post<<<preBlocks, 512, 0, stream>>>(h, hzd, hzs, rowptr, precs,
            bcomb + (size_t)l * 512 * 256,
            ampv, attv,
            pkPostHi + (size_t)l * 2 * 106496, pkPostLo + (size_t)l * 2 * 106496,
            post_b + l * 2 * 64,
            pkLinHi + (size_t)l * 16384, pkLinLo + (size_t)l * 16384,
            lin_b + l * 128,
            o2, stats + l * 256);
    }

    k_pool<<<(NN + 63) / 64, 128, 0, stream>>>(o2, stats + 2 * 256,
        bn_g + 2 * 128, bn_b + 2 * 128, batch, g0);

    k_head_gemm<<<NG, 128, 0, stream>>>(g0, mlp_W, mlp_b, gA, hstats, 128, 128);
    k_head_fused<<<NG, 128, 0, stream>>>(gA, hstats, mlp_g, mlp_be,
        mlp_W + 128 * 128, mlp_b + 128, gB, hstats + 256, 128, 128);
    k_head_fused<<<NG, 128, 0, stream>>>(gB, hstats + 256, mlp_g + 128, mlp_be + 128,
        hW1, hb1, gA, hstats + 512, 128, 64);
    k_head_fused<<<NG, 128, 0, stream>>>(gA, hstats + 512, hg1, hbe1,
        hW2, hb2, gB, hstats + 768, 64, 32);
    k_head_fused<<<NG, 128, 0, stream>>>(gB, hstats + 768, hg2, hbe2,
        hW3, hb3, out, (float*)nullptr, 32, 3);
}

// Round 17
// 920.866 us; speedup vs baseline: 1.2374x; 1.2374x over previous
//
#include <hip/hip_runtime.h>
#include <math.h>

// PNA GNN forward, MI355X. Round 17: revert to round-15 (best: 929us).
// r16 post-mortem: 32-node/512-thr k_post halved B L2 traffic but LDS 104KB
// -> 1 block/CU (occ 20%), bank conflicts 2x, 512-thr barriers => +58us/launch.
// The r8/r15 shape (256thr, 16 nodes, staged h, 3 blocks/CU) is the empirical
// floor across 9 k_post interventions (r5,r9-r16). Locking it in.

#define NN 50000
#define NE 200000
#define HD 128
#define NG 1000
#define EPSV 1e-5f
#define ALOGC 1.1330197327247628f

#define AP 1288    // a_lds row pitch (ushorts)
#define OPF 132    // o_f row pitch (floats)
#define ECAP 512
#define SCB 49

typedef __bf16 bf16x8 __attribute__((ext_vector_type(8)));
typedef float f32x4 __attribute__((ext_vector_type(4)));

__device__ __forceinline__ unsigned short f2bf(float f) {
    unsigned int u = __float_as_uint(f);
    unsigned int r = (u + 0x7FFFu + ((u >> 16) & 1u)) >> 16;
    return (unsigned short)r;
}
__device__ __forceinline__ float bf2f(unsigned short h) {
    return __uint_as_float((unsigned int)h << 16);
}

__global__ void k_fill(float* __restrict__ o, float v, int n) {
    int i = blockIdx.x * 256 + threadIdx.x;
    if (i < n) o[i] = v;
}

__global__ void k_zero(float* __restrict__ z, int n) {
    int i = blockIdx.x * 256 + threadIdx.x;
    if (i < n) z[i] = 0.f;
}

// ---------------- node encoder ----------------
__global__ __launch_bounds__(256) void k_encode_nodes(
    const int* __restrict__ x, const float* __restrict__ aemb, float* __restrict__ h) {
    __shared__ int xi[8][9];
    int nb = blockIdx.x * 8;
    int tid = threadIdx.x;
    if (tid < 72) xi[tid / 9][tid % 9] = x[nb * 9 + tid];
    __syncthreads();
    int node = tid >> 5, c4 = (tid & 31) * 4;
    float4 acc = make_float4(0.f, 0.f, 0.f, 0.f);
#pragma unroll
    for (int f = 0; f < 9; ++f) {
        float4 e = *(const float4*)(aemb + (size_t)(f * 64 + xi[node][f]) * HD + c4);
        acc.x += e.x; acc.y += e.y; acc.z += e.z; acc.w += e.w;
    }
    *(float4*)(h + (size_t)(nb + node) * HD + c4) = acc;
}

// ---------------- CSR build (parallel scan) ----------------
__global__ void k_count(const int* __restrict__ dst, int* __restrict__ cnt) {
    int e = blockIdx.x * 256 + threadIdx.x;
    if (e < NE) atomicAdd(&cnt[dst[e]], 1);
}

__global__ __launch_bounds__(1024) void k_scanA(const int* __restrict__ cnt,
                                                int* __restrict__ sc, int* __restrict__ tot) {
    __shared__ int buf[1024];
    int tid = threadIdx.x;
    int i = blockIdx.x * 1024 + tid;
    int v = (i < NN) ? cnt[i] : 0;
    buf[tid] = v;
    __syncthreads();
    for (int s = 1; s < 1024; s <<= 1) {
        int t = (tid >= s) ? buf[tid - s] : 0;
        __syncthreads();
        buf[tid] += t;
        __syncthreads();
    }
    if (i < NN) sc[i] = buf[tid];
    if (tid == 1023) tot[blockIdx.x] = buf[1023];
}

__global__ void k_scanB(const int* __restrict__ tot, int* __restrict__ offb) {
    if (threadIdx.x == 0) {
        int run = 0;
        for (int b = 0; b < SCB; ++b) { offb[b] = run; run += tot[b]; }
    }
}

__global__ __launch_bounds__(1024) void k_scanC(
    const int* __restrict__ cnt, const int* __restrict__ sc, const int* __restrict__ offb,
    int* __restrict__ rowptr, float* __restrict__ ampv, float* __restrict__ attv) {
    int i = blockIdx.x * 1024 + threadIdx.x;
    if (i == 0) rowptr[0] = 0;
    if (i < NN) {
        rowptr[i + 1] = offb[blockIdx.x] + sc[i];
        int v = cnt[i];
        float dg = (float)(v > 0 ? v : 1);
        float lg = logf(dg + 1.0f);
        ampv[i] = lg / ALOGC;
        attv[i] = ALOGC / lg;
    }
}

__global__ void k_scatter(const int* __restrict__ ei, const int* __restrict__ eai,
                          const int* __restrict__ rowptr,
                          int* __restrict__ fill, int* __restrict__ precs) {
    int e = blockIdx.x * 256 + threadIdx.x;
    if (e < NE) {
        int d = ei[NE + e];
        int pos = rowptr[d] + atomicAdd(&fill[d], 1);
        int cidx = eai[e * 3] | (eai[e * 3 + 1] << 3) | (eai[e * 3 + 2] << 6);
        precs[pos] = ei[e] | (cidx << 17);
    }
}

// ---------------- fold edge_W into pre_W chunk3 ----------------
__global__ void k_fold(const float* __restrict__ edge_W, const float* __restrict__ edge_b,
                       const float* __restrict__ pre_W, const float* __restrict__ pre_b,
                       float* __restrict__ cW, float* __restrict__ tb) {
    int l = blockIdx.y;
    int k = blockIdx.x;
    int tj = threadIdx.x;
    int t = tj >> 7, j = tj & 127;
    const float* pw = pre_W + ((size_t)(l * 2 + t) * 384 + 256) * 128 + j;
    if (k < 128) {
        const float* ew = edge_W + ((size_t)l * 128 + k) * 128;
        float acc = 0.f;
        for (int i = 0; i < 128; ++i) acc += ew[i] * pw[i * 128];
        cW[((size_t)l * 128 + k) * 256 + tj] = acc;
    } else {
        const float* eb = edge_b + l * 128;
        float acc = pre_b[(l * 2 + t) * 128 + j];
        for (int i = 0; i < 128; ++i) acc += eb[i] * pw[i * 128];
        tb[l * 256 + tj] = acc;
    }
}

// ---------------- combined bond table, direct from bemb ----------------
__global__ void k_bcomb2(const float* __restrict__ bemb, const float* __restrict__ cW,
                         unsigned short* __restrict__ bcomb) {
    int ci = blockIdx.x, l = blockIdx.y, tj = threadIdx.x;
    const float* s0 = bemb + (size_t)(0 * 8 + (ci & 7)) * 128;
    const float* s1 = bemb + (size_t)(1 * 8 + ((ci >> 3) & 7)) * 128;
    const float* s2 = bemb + (size_t)(2 * 8 + (ci >> 6)) * 128;
    const float* w = cW + (size_t)l * 128 * 256;
    float acc = 0.f;
    for (int i = 0; i < 128; ++i) acc += (s0[i] + s1[i] + s2[i]) * w[i * 256 + tj];
    bcomb[((size_t)l * 512 + ci) * 256 + tj] = f2bf(acc);
}

// ---------------- merged weight packing (hi/lo planes) ----------------
__device__ __forceinline__ void pack_body2(const float* __restrict__ W, int N, int NT,
                                           unsigned short* __restrict__ pkh,
                                           unsigned short* __restrict__ pkl,
                                           int blk, int lane) {
    int kstep = blk / NT, nt = blk - kstep * NT;
    int kb = kstep * 32 + (lane >> 4) * 8;
    int col = nt * 16 + (lane & 15);
    unsigned short th[8], tl[8];
#pragma unroll
    for (int i = 0; i < 8; ++i) {
        float w = W[(size_t)(kb + i) * N + col];
        unsigned short hh = f2bf(w);
        th[i] = hh;
        tl[i] = f2bf(w - bf2f(hh));
    }
    size_t base = ((size_t)blk * 64 + lane) * 8;
    *(uint4*)(pkh + base) = *(uint4*)th;
    *(uint4*)(pkl + base) = *(uint4*)tl;
}

__global__ __launch_bounds__(64) void k_packall(
    const float* __restrict__ post_W, const float* __restrict__ lin_W,
    const float* __restrict__ pre_W,
    unsigned short* __restrict__ pkPostHi, unsigned short* __restrict__ pkPostLo,
    unsigned short* __restrict__ pkLinHi, unsigned short* __restrict__ pkLinLo,
    unsigned short* __restrict__ pkPreHi, unsigned short* __restrict__ pkPreLo) {
    int b = blockIdx.x;
    int lane = threadIdx.x;
    if (b < 1248) {
        int l = b / 416, rem = b % 416;
        int t = rem / 208, blk = rem % 208;
        size_t off = ((size_t)l * 2 + t) * 106496;
        pack_body2(post_W + ((size_t)l * 2 + t) * 1664 * 64, 64, 4,
                   pkPostHi + off, pkPostLo + off, blk, lane);
    } else if (b < 1344) {
        int idx = b - 1248;
        int l = idx / 32, blk = idx % 32;
        pack_body2(lin_W + (size_t)l * 128 * 128, 128, 8,
                   pkLinHi + (size_t)l * 16384, pkLinLo + (size_t)l * 16384, blk, lane);
    } else {
        int idx = b - 1344;
        int l = idx / 128, bb = idx % 128;
        const float* preW = pre_W + (size_t)l * 2 * 384 * 128;
        unsigned short* phi = pkPreHi + (size_t)l * 65536;
        unsigned short* plo = pkPreLo + (size_t)l * 65536;
        int kstep = bb >> 5, nt = bb & 31;
        int q = lane >> 4, nc = lane & 15;
        int col = nt * 16 + nc;
        int t = (col >> 7) & 1;
        int jcol = col & 127;
        int fbase = (col < 256) ? 0 : 128;
        unsigned short hi[8], lo[8];
#pragma unroll
        for (int i = 0; i < 8; ++i) {
            int k = kstep * 32 + q * 8 + i;
            float w = preW[((size_t)t * 384 + fbase + k) * 128 + jcol];
            unsigned short h16 = f2bf(w);
            hi[i] = h16;
            lo[i] = f2bf(w - bf2f(h16));
        }
        size_t base = ((size_t)bb * 64 + lane) * 8;
        *(uint4*)(phi + base) = *(uint4*)hi;
        *(uint4*)(plo + base) = *(uint4*)lo;
    }
}

// ---------------- pre-transform MFMA body: 2 M-tiles share B loads ----------
__device__ __forceinline__ void pre_mfma_body2(
    const unsigned short* __restrict__ ah, const unsigned short* __restrict__ al,
    const unsigned short* __restrict__ phi, const unsigned short* __restrict__ plo,
    const float* __restrict__ tb, int n0, int tid,
    unsigned short* __restrict__ hzd, unsigned short* __restrict__ hzs) {
    int lane = tid & 63, w = tid >> 6;
    int q = lane >> 4, nc = lane & 15;
    f32x4 acc0[8], acc1[8];
#pragma unroll
    for (int j = 0; j < 8; ++j) {
        acc0[j] = (f32x4){0.f, 0.f, 0.f, 0.f};
        acc1[j] = (f32x4){0.f, 0.f, 0.f, 0.f};
    }
#pragma unroll
    for (int kk = 0; kk < 4; ++kk) {
        bf16x8 Ahi0 = *(const bf16x8*)(ah + nc * 136 + kk * 32 + q * 8);
        bf16x8 Alo0 = *(const bf16x8*)(al + nc * 136 + kk * 32 + q * 8);
        bf16x8 Ahi1 = *(const bf16x8*)(ah + (16 + nc) * 136 + kk * 32 + q * 8);
        bf16x8 Alo1 = *(const bf16x8*)(al + (16 + nc) * 136 + kk * 32 + q * 8);
#pragma unroll
        for (int j = 0; j < 8; ++j) {
            int nt = w * 8 + j;
            size_t base = ((size_t)(kk * 32 + nt) * 64 + lane) * 8;
            bf16x8 Bhi = *(const bf16x8*)(phi + base);
            bf16x8 Blo = *(const bf16x8*)(plo + base);
            acc0[j] = __builtin_amdgcn_mfma_f32_16x16x32_bf16(Ahi0, Bhi, acc0[j], 0, 0, 0);
            acc0[j] = __builtin_amdgcn_mfma_f32_16x16x32_bf16(Ahi0, Blo, acc0[j], 0, 0, 0);
            acc0[j] = __builtin_amdgcn_mfma_f32_16x16x32_bf16(Alo0, Bhi, acc0[j], 0, 0, 0);
            acc1[j] = __builtin_amdgcn_mfma_f32_16x16x32_bf16(Ahi1, Bhi, acc1[j], 0, 0, 0);
            acc1[j] = __builtin_amdgcn_mfma_f32_16x16x32_bf16(Ahi1, Blo, acc1[j], 0, 0, 0);
            acc1[j] = __builtin_amdgcn_mfma_f32_16x16x32_bf16(Alo1, Bhi, acc1[j], 0, 0, 0);
        }
    }
#pragma unroll
    for (int j = 0; j < 8; ++j) {
        int col = (w * 8 + j) * 16 + nc;
        float bias = (col < 256) ? tb[col] : 0.f;
#pragma unroll
        for (int reg = 0; reg < 4; ++reg) {
            int r0 = n0 + q * 4 + reg;
            int r1 = r0 + 16;
            if (col < 256) {
                if (r0 < NN) hzd[(size_t)r0 * 256 + col] = f2bf(acc0[j][reg] + bias);
                if (r1 < NN) hzd[(size_t)r1 * 256 + col] = f2bf(acc1[j][reg] + bias);
            } else {
                if (r0 < NN) hzs[(size_t)r0 * 256 + (col - 256)] = f2bf(acc0[j][reg]);
                if (r1 < NN) hzs[(size_t)r1 * 256 + (col - 256)] = f2bf(acc1[j][reg]);
            }
        }
    }
}

// ---------------- node pre-transform via MFMA (layer 0), 32 nodes/block ------
__global__ __launch_bounds__(256) void k_pre_m(
    const float* __restrict__ h,
    const unsigned short* __restrict__ phi, const unsigned short* __restrict__ plo,
    const float* __restrict__ tb,
    unsigned short* __restrict__ hzd, unsigned short* __restrict__ hzs) {
    __shared__ __align__(16) unsigned short ah[32 * 136];
    __shared__ __align__(16) unsigned short al[32 * 136];
    int n0 = blockIdx.x * 32;
    int tid = threadIdx.x;
    for (int half = 0; half < 2; ++half) {
        int node = (tid >> 4) + half * 16, cg = (tid & 15) * 8;
        int n = n0 + node;
        unsigned short hh[8] = {0, 0, 0, 0, 0, 0, 0, 0};
        unsigned short ll[8] = {0, 0, 0, 0, 0, 0, 0, 0};
        if (n < NN) {
            const float* hs = h + (size_t)n * HD + cg;
            float4 v0 = *(const float4*)(hs);
            float4 v1 = *(const float4*)(hs + 4);
            float vv[8] = {v0.x, v0.y, v0.z, v0.w, v1.x, v1.y, v1.z, v1.w};
#pragma unroll
            for (int i = 0; i < 8; ++i) {
                hh[i] = f2bf(vv[i]);
                ll[i] = f2bf(vv[i] - bf2f(hh[i]));
            }
        }
        *(uint4*)(ah + node * 136 + cg) = *(uint4*)hh;
        *(uint4*)(al + node * 136 + cg) = *(uint4*)ll;
    }
    __syncthreads();
    pre_mfma_body2(ah, al, phi, plo, tb, n0, tid, hzd, hzs);
}

// ---------------- fused BN+ReLU+pre-transform (layers 1,2), 32 nodes/block ----
__global__ __launch_bounds__(256) void k_bnpre(
    const float* __restrict__ o2, const float* __restrict__ stats,
    const float* __restrict__ g, const float* __restrict__ b,
    const unsigned short* __restrict__ phi, const unsigned short* __restrict__ plo,
    const float* __restrict__ tb,
    float* __restrict__ h, unsigned short* __restrict__ hzd, unsigned short* __restrict__ hzs) {
    __shared__ __align__(16) unsigned short ah[32 * 136];
    __shared__ __align__(16) unsigned short al[32 * 136];
    int n0 = blockIdx.x * 32;
    int tid = threadIdx.x;
    for (int half = 0; half < 2; ++half) {
        int node = (tid >> 4) + half * 16, cg = (tid & 15) * 8;
        int n = n0 + node;
        unsigned short hh[8] = {0, 0, 0, 0, 0, 0, 0, 0};
        unsigned short ll[8] = {0, 0, 0, 0, 0, 0, 0, 0};
        if (n < NN) {
            const float* os = o2 + (size_t)n * HD + cg;
            float4 v0 = *(const float4*)(os);
            float4 v1 = *(const float4*)(os + 4);
            float vv[8] = {v0.x, v0.y, v0.z, v0.w, v1.x, v1.y, v1.z, v1.w};
            float ou[8];
#pragma unroll
            for (int i = 0; i < 8; ++i) {
                int c = cg + i;
                float mu = stats[c] * (1.f / NN);
                float var = stats[128 + c] * (1.f / NN) - mu * mu;
                float val = (vv[i] - mu) * rsqrtf(var + EPSV) * g[c] + b[c];
                val = fmaxf(val, 0.f);
                ou[i] = val;
                hh[i] = f2bf(val);
                ll[i] = f2bf(val - bf2f(hh[i]));
            }
            float* hd = h + (size_t)n * HD + cg;
            *(float4*)(hd) = make_float4(ou[0], ou[1], ou[2], ou[3]);
            *(float4*)(hd + 4) = make_float4(ou[4], ou[5], ou[6], ou[7]);
        }
        *(uint4*)(ah + node * 136 + cg) = *(uint4*)hh;
        *(uint4*)(al + node * 136 + cg) = *(uint4*)ll;
    }
    __syncthreads();
    pre_mfma_body2(ah, al, phi, plo, tb, n0, tid, hzd, hzs);
}

// ---------------- fused: message + agg -> bf16 LDS -> MFMA post + lin + BN stats ----
__global__ __launch_bounds__(256) void k_post(
    const float* __restrict__ h,
    const unsigned short* __restrict__ hzd, const unsigned short* __restrict__ hzs,
    const int* __restrict__ rowptr, const int* __restrict__ precs,
    const unsigned short* __restrict__ bcomb,
    const float* __restrict__ ampv, const float* __restrict__ attv,
    const unsigned short* __restrict__ pkPostHi, const unsigned short* __restrict__ pkPostLo,
    const float* __restrict__ postb,
    const unsigned short* __restrict__ pkLinHi, const unsigned short* __restrict__ pkLinLo,
    const float* __restrict__ linb,
    float* __restrict__ o2, float* __restrict__ stats) {
    __shared__ __align__(16) unsigned short a_lds[16 * AP];   // 41216 B
    __shared__ __align__(16) float o_f[16 * OPF];             // 8448 B
    __shared__ int es[ECAP];                                  // 2048 B
    __shared__ float s_amp[16], s_att[16];
    int n0 = blockIdx.x * 16;
    int tid = threadIdx.x;

    int pbase = rowptr[n0];
    int ecount = rowptr[n0 + 16] - pbase;
    for (int i = tid; i < ecount && i < ECAP; i += 256) es[i] = precs[pbase + i];
    {   // stage h tile -> bf16, duplicated into both t-sections
        int node = tid >> 4, cg = (tid & 15) * 8;
        const float* hs = h + (size_t)(n0 + node) * HD + cg;
        float4 v0 = *(const float4*)(hs);
        float4 v1 = *(const float4*)(hs + 4);
        unsigned short* d0 = a_lds + node * AP + cg;
        unsigned short* d1 = d0 + 640;
        unsigned short bb[8];
        bb[0] = f2bf(v0.x); bb[1] = f2bf(v0.y); bb[2] = f2bf(v0.z); bb[3] = f2bf(v0.w);
        bb[4] = f2bf(v1.x); bb[5] = f2bf(v1.y); bb[6] = f2bf(v1.z); bb[7] = f2bf(v1.w);
#pragma unroll
        for (int i = 0; i < 8; ++i) { d0[i] = bb[i]; d1[i] = bb[i]; }
    }
    if (tid < 16) { s_amp[tid] = ampv[n0 + tid]; s_att[tid] = attv[n0 + tid]; }
    __syncthreads();

    // ---- phase A: 2-node interleaved edge loops, bf16 gathers, es staged ----
    {
        int wv = tid >> 6, lane = tid & 63;
        int cc = lane * 4;
        int tt = cc >> 7, jj = cc & 127;
        bool incap = (ecount <= ECAP);
        const float4 Z4 = make_float4(0.f, 0.f, 0.f, 0.f);
        const float4 BIG = make_float4(3.4e38f, 3.4e38f, 3.4e38f, 3.4e38f);
        const float4 NBIG = make_float4(-3.4e38f, -3.4e38f, -3.4e38f, -3.4e38f);

#define EDGE_ACC(P, S1, S2, MN, MX)                                                       \
        {                                                                                 \
            int rec = incap ? es[(P) - pbase] : precs[(P)];                               \
            int sp = rec & 131071;                                                        \
            int ci = rec >> 17;                                                           \
            uint2 uv = *(const uint2*)(hzs + (size_t)sp * 256 + cc);                      \
            uint2 ub = *(const uint2*)(bcomb + (size_t)ci * 256 + cc);                    \
            float wx = __uint_as_float(uv.x << 16) + __uint_as_float(ub.x << 16);         \
            float wy = __uint_as_float(uv.x & 0xffff0000u) + __uint_as_float(ub.x & 0xffff0000u); \
            float wz = __uint_as_float(uv.y << 16) + __uint_as_float(ub.y << 16);         \
            float ww = __uint_as_float(uv.y & 0xffff0000u) + __uint_as_float(ub.y & 0xffff0000u); \
            S1.x += wx; S1.y += wy; S1.z += wz; S1.w += ww;                               \
            S2.x += wx * wx; S2.y += wy * wy; S2.z += wz * wz; S2.w += ww * ww;           \
            MN.x = fminf(MN.x, wx); MN.y = fminf(MN.y, wy);                               \
            MN.z = fminf(MN.z, wz); MN.w = fminf(MN.w, ww);                               \
            MX.x = fmaxf(MX.x, wx); MX.y = fmaxf(MX.y, wy);                               \
            MX.z = fmaxf(MX.z, wz); MX.w = fmaxf(MX.w, ww);                               \
        }

        auto fin = [&](int r, int cnt, float4 hd, float4 s1, float4 s2, float4 mn, float4 mx) {
            float inv = 1.f / (float)(cnt > 0 ? cnt : 1);
            float4 mw, stdv, mean;
            mw.x = s1.x * inv; mw.y = s1.y * inv; mw.z = s1.z * inv; mw.w = s1.w * inv;
            stdv.x = sqrtf(fmaxf(s2.x * inv - mw.x * mw.x, 0.f) + EPSV);
            stdv.y = sqrtf(fmaxf(s2.y * inv - mw.y * mw.y, 0.f) + EPSV);
            stdv.z = sqrtf(fmaxf(s2.z * inv - mw.z * mw.z, 0.f) + EPSV);
            stdv.w = sqrtf(fmaxf(s2.w * inv - mw.w * mw.w, 0.f) + EPSV);
            if (cnt > 0) {
                mean.x = hd.x + mw.x; mean.y = hd.y + mw.y;
                mean.z = hd.z + mw.z; mean.w = hd.w + mw.w;
                mn.x += hd.x; mn.y += hd.y; mn.z += hd.z; mn.w += hd.w;
                mx.x += hd.x; mx.y += hd.y; mx.z += hd.z; mx.w += hd.w;
            } else {
                mean = Z4; mn = Z4; mx = Z4;
            }
            unsigned short* d = a_lds + r * AP + tt * 640 + 128 + jj;
            d[0] = f2bf(mean.x); d[1] = f2bf(mean.y); d[2] = f2bf(mean.z); d[3] = f2bf(mean.w);
            d += 128; d[0] = f2bf(mn.x); d[1] = f2bf(mn.y); d[2] = f2bf(mn.z); d[3] = f2bf(mn.w);
            d += 128; d[0] = f2bf(mx.x); d[1] = f2bf(mx.y); d[2] = f2bf(mx.z); d[3] = f2bf(mx.w);
            d += 128; d[0] = f2bf(stdv.x); d[1] = f2bf(stdv.y); d[2] = f2bf(stdv.z); d[3] = f2bf(stdv.w);
        };

        for (int i = 0; i < 2; ++i) {
            int ra = wv * 4 + i * 2;
            int rb = ra + 1;
            int na = n0 + ra, nb = n0 + rb;
            int pa0 = rowptr[na], pa1 = rowptr[na + 1];
            int pb0 = rowptr[nb], pb1 = rowptr[nb + 1];
            uint2 uda = *(const uint2*)(hzd + (size_t)na * 256 + cc);
            uint2 udb = *(const uint2*)(hzd + (size_t)nb * 256 + cc);
            float4 hda, hdb;
            hda.x = __uint_as_float(uda.x << 16); hda.y = __uint_as_float(uda.x & 0xffff0000u);
            hda.z = __uint_as_float(uda.y << 16); hda.w = __uint_as_float(uda.y & 0xffff0000u);
            hdb.x = __uint_as_float(udb.x << 16); hdb.y = __uint_as_float(udb.x & 0xffff0000u);
            hdb.z = __uint_as_float(udb.y << 16); hdb.w = __uint_as_float(udb.y & 0xffff0000u);
            float4 s1a = Z4, s2a = Z4, mna = BIG, mxa = NBIG;
            float4 s1b = Z4, s2b = Z4, mnb = BIG, mxb = NBIG;
            int da = pa1 - pa0, db = pb1 - pb0;
            int mc = (da < db) ? da : db;
            for (int k = 0; k < mc; ++k) {
                EDGE_ACC(pa0 + k, s1a, s2a, mna, mxa)
                EDGE_ACC(pb0 + k, s1b, s2b, mnb, mxb)
            }
            for (int k = mc; k < da; ++k) EDGE_ACC(pa0 + k, s1a, s2a, mna, mxa)
            for (int k = mc; k < db; ++k) EDGE_ACC(pb0 + k, s1b, s2b, mnb, mxb)
            fin(ra, da, hda, s1a, s2a, mna, mxa);
            fin(rb, db, hdb, s1b, s2b, mnb, mxb);
        }
#undef EDGE_ACC
    }
    __syncthreads();

    // ---- phase B: post GEMM via MFMA, B-side hi/lo ----
    {
        int lane = tid & 63;
        int w = tid >> 6;
        int t = w >> 1;
        int ntb = (w & 1) * 2;
        int q = lane >> 4, nc = lane & 15;
        const unsigned short* arow = a_lds + (size_t)nc * AP + t * 640 + q * 8;
        size_t toff = (size_t)t * 106496;
        const unsigned short* pkh = pkPostHi + toff;
        const unsigned short* pkl = pkPostLo + toff;
        f32x4 aP0 = {0.f, 0.f, 0.f, 0.f}, aP1 = {0.f, 0.f, 0.f, 0.f};
        f32x4 aA0 = {0.f, 0.f, 0.f, 0.f}, aA1 = {0.f, 0.f, 0.f, 0.f};
        f32x4 aT0 = {0.f, 0.f, 0.f, 0.f}, aT1 = {0.f, 0.f, 0.f, 0.f};
        for (int kk = 0; kk < 20; ++kk) {
            bf16x8 af = *(const bf16x8*)(arow + kk * 32);
            size_t ib = ((size_t)(kk * 4 + ntb) * 64 + lane) * 8;
            aP0 = __builtin_amdgcn_mfma_f32_16x16x32_bf16(af, *(const bf16x8*)(pkh + ib), aP0, 0, 0, 0);
            aP0 = __builtin_amdgcn_mfma_f32_16x16x32_bf16(af, *(const bf16x8*)(pkl + ib), aP0, 0, 0, 0);
            aP1 = __builtin_amdgcn_mfma_f32_16x16x32_bf16(af, *(const bf16x8*)(pkh + ib + 512), aP1, 0, 0, 0);
            aP1 = __builtin_amdgcn_mfma_f32_16x16x32_bf16(af, *(const bf16x8*)(pkl + ib + 512), aP1, 0, 0, 0);
            if (kk >= 4) {
                size_t ia = ((size_t)((kk + 16) * 4 + ntb) * 64 + lane) * 8;
                aA0 = __builtin_amdgcn_mfma_f32_16x16x32_bf16(af, *(const bf16x8*)(pkh + ia), aA0, 0, 0, 0);
                aA0 = __builtin_amdgcn_mfma_f32_16x16x32_bf16(af, *(const bf16x8*)(pkl + ia), aA0, 0, 0, 0);
                aA1 = __builtin_amdgcn_mfma_f32_16x16x32_bf16(af, *(const bf16x8*)(pkh + ia + 512), aA1, 0, 0, 0);
                aA1 = __builtin_amdgcn_mfma_f32_16x16x32_bf16(af, *(const bf16x8*)(pkl + ia + 512), aA1, 0, 0, 0);
                size_t it = ((size_t)((kk + 32) * 4 + ntb) * 64 + lane) * 8;
                aT0 = __builtin_amdgcn_mfma_f32_16x16x32_bf16(af, *(const bf16x8*)(pkh + it), aT0, 0, 0, 0);
                aT0 = __builtin_amdgcn_mfma_f32_16x16x32_bf16(af, *(const bf16x8*)(pkl + it), aT0, 0, 0, 0);
                aT1 = __builtin_amdgcn_mfma_f32_16x16x32_bf16(af, *(const bf16x8*)(pkh + it + 512), aT1, 0, 0, 0);
                aT1 = __builtin_amdgcn_mfma_f32_16x16x32_bf16(af, *(const bf16x8*)(pkl + it + 512), aT1, 0, 0, 0);
            }
        }
#pragma unroll
        for (int u = 0; u < 2; ++u) {
            int nt = ntb + u;
            int col = t * 64 + nt * 16 + nc;
            float pbia = postb[t * 64 + nt * 16 + nc];
            f32x4 P = u ? aP1 : aP0;
            f32x4 A = u ? aA1 : aA0;
            f32x4 T = u ? aT1 : aT0;
#pragma unroll
            for (int reg = 0; reg < 4; ++reg) {
                int mrow = q * 4 + reg;
                o_f[mrow * OPF + col] = P[reg] + s_amp[mrow] * A[reg] + s_att[mrow] * T[reg] + pbia;
            }
        }
    }
    __syncthreads();

    // ---- lin GEMM via MFMA: fp32 A split hi/lo on the fly, B hi/lo (3-product) ----
    {
        int lane = tid & 63;
        int w = tid >> 6;
        int ntb = w * 2;
        int q = lane >> 4, nc = lane & 15;
        const float* arow = o_f + (size_t)nc * OPF + q * 8;
        f32x4 L0 = {0.f, 0.f, 0.f, 0.f}, L1 = {0.f, 0.f, 0.f, 0.f};
#pragma unroll
        for (int kk = 0; kk < 4; ++kk) {
            float4 a0 = *(const float4*)(arow + kk * 32);
            float4 a1 = *(const float4*)(arow + kk * 32 + 4);
            float vv[8] = {a0.x, a0.y, a0.z, a0.w, a1.x, a1.y, a1.z, a1.w};
            unsigned short hh[8], ll[8];
#pragma unroll
            for (int i = 0; i < 8; ++i) {
                hh[i] = f2bf(vv[i]);
                ll[i] = f2bf(vv[i] - bf2f(hh[i]));
            }
            bf16x8 Ahi = *(const bf16x8*)hh;
            bf16x8 Alo = *(const bf16x8*)ll;
            size_t ib = ((size_t)(kk * 8 + ntb) * 64 + lane) * 8;
            bf16x8 B0h = *(const bf16x8*)(pkLinHi + ib);
            bf16x8 B0l = *(const bf16x8*)(pkLinLo + ib);
            bf16x8 B1h = *(const bf16x8*)(pkLinHi + ib + 512);
            bf16x8 B1l = *(const bf16x8*)(pkLinLo + ib + 512);
            L0 = __builtin_amdgcn_mfma_f32_16x16x32_bf16(Ahi, B0h, L0, 0, 0, 0);
            L0 = __builtin_amdgcn_mfma_f32_16x16x32_bf16(Alo, B0h, L0, 0, 0, 0);
            L0 = __builtin_amdgcn_mfma_f32_16x16x32_bf16(Ahi, B0l, L0, 0, 0, 0);
            L1 = __builtin_amdgcn_mfma_f32_16x16x32_bf16(Ahi, B1h, L1, 0, 0, 0);
            L1 = __builtin_amdgcn_mfma_f32_16x16x32_bf16(Alo, B1h, L1, 0, 0, 0);
            L1 = __builtin_amdgcn_mfma_f32_16x16x32_bf16(Ahi, B1l, L1, 0, 0, 0);
        }
#pragma unroll
        for (int u = 0; u < 2; ++u) {
            int col = (ntb + u) * 16 + nc;
            float lb = linb[col];
            f32x4 L = u ? L1 : L0;
            float ps = 0.f, pss = 0.f;
#pragma unroll
            for (int reg = 0; reg < 4; ++reg) {
                int mrow = q * 4 + reg;
                float v = L[reg] + lb;
                o2[(size_t)(n0 + mrow) * HD + col] = v;
                ps += v; pss += v * v;
            }
            ps += __shfl_down(ps, 16); ps += __shfl_down(ps, 32);
            pss += __shfl_down(pss, 16); pss += __shfl_down(pss, 32);
            if (q == 0) {
                atomicAdd(&stats[col], ps);
                atomicAdd(&stats[128 + col], pss);
            }
        }
    }
}

// ---------------- graph pooling with fused final BN+ReLU ----------------
__global__ void k_pool(const float* __restrict__ o2, const float* __restrict__ stats,
                       const float* __restrict__ g, const float* __restrict__ b,
                       const int* __restrict__ batch, float* __restrict__ g0) {
    int c = threadIdx.x;
    float mu = stats[c] * (1.f / NN);
    float var = stats[128 + c] * (1.f / NN) - mu * mu;
    float rs = rsqrtf(var + EPSV) * g[c];
    float bb = b[c];
    int nbase = blockIdx.x * 64;
    float run = 0.f; int cur = -1;
    for (int i = 0; i < 64; ++i) {
        int n = nbase + i;
        if (n >= NN) break;
        int bi = batch[n];
        if (bi != cur) {
            if (cur >= 0) atomicAdd(&g0[(size_t)cur * HD + c], run);
            cur = bi; run = 0.f;
        }
        run += fmaxf((o2[(size_t)n * HD + c] - mu) * rs + bb, 0.f);
    }
    if (cur >= 0) atomicAdd(&g0[(size_t)cur * HD + c], run);
}

// ---------------- head ----------------
__global__ void k_head_gemm(const float* __restrict__ x, const float* __restrict__ W,
                            const float* __restrict__ b, float* __restrict__ y,
                            float* __restrict__ stats, int K, int Kout) {
    int row = blockIdx.x;
    int col = threadIdx.x;
    if (col >= Kout) return;
    float acc = b[col];
    for (int k = 0; k < K; k += 4) {
        float4 xv = *(const float4*)(x + (size_t)row * K + k);
        acc += xv.x * W[(k + 0) * Kout + col] + xv.y * W[(k + 1) * Kout + col]
             + xv.z * W[(k + 2) * Kout + col] + xv.w * W[(k + 3) * Kout + col];
    }
    y[(size_t)row * Kout + col] = acc;
    if (stats) {
        atomicAdd(&stats[col], acc);
        atomicAdd(&stats[Kout + col], acc * acc);
    }
}

__global__ __launch_bounds__(128) void k_head_fused(
    const float* __restrict__ y_in, const float* __restrict__ stats_in,
    const float* __restrict__ g, const float* __restrict__ b,
    const float* __restrict__ W, const float* __restrict__ bias,
    float* __restrict__ y_out, float* __restrict__ stats_out, int Kin, int Kout) {
    __shared__ float row[128];
    int r = blockIdx.x, tid = threadIdx.x;
    if (tid < Kin) {
        float mu = stats_in[tid] * (1.f / NG);
        float var = stats_in[Kin + tid] * (1.f / NG) - mu * mu;
        float v = (y_in[(size_t)r * Kin + tid] - mu) * rsqrtf(var + EPSV) * g[tid] + b[tid];
        row[tid] = fmaxf(v, 0.f);
    }
    __syncthreads();
    if (tid < Kout) {
        float acc = bias[tid];
        for (int k = 0; k < Kin; ++k) acc += row[k] * W[(size_t)k * Kout + tid];
        y_out[(size_t)r * Kout + tid] = acc;
        if (stats_out) {
            atomicAdd(&stats_out[tid], acc);
            atomicAdd(&stats_out[Kout + tid], acc * acc);
        }
    }
}

extern "C" void kernel_launch(void* const* d_in, const int* in_sizes, int n_in,
                              void* d_out, int out_size, void* d_ws, size_t ws_size,
                              hipStream_t stream) {
    const int*   x        = (const int*)  d_in[0];
    const int*   ei       = (const int*)  d_in[1];
    const int*   batch    = (const int*)  d_in[2];
    const int*   eai      = (const int*)  d_in[3];
    const float* atom_emb = (const float*)d_in[4];
    const float* bond_emb = (const float*)d_in[5];
    const float* edge_W   = (const float*)d_in[6];
    const float* edge_b   = (const float*)d_in[7];
    const float* pre_W    = (const float*)d_in[8];
    const float* pre_b    = (const float*)d_in[9];
    const float* post_W   = (const float*)d_in[10];
    const float* post_b   = (const float*)d_in[11];
    const float* lin_W    = (const float*)d_in[12];
    const float* lin_b    = (const float*)d_in[13];
    const float* bn_g     = (const float*)d_in[14];
    const float* bn_b     = (const float*)d_in[15];
    const float* mlp_W    = (const float*)d_in[16];
    const float* mlp_b    = (const float*)d_in[17];
    const float* mlp_g    = (const float*)d_in[18];
    const float* mlp_be   = (const float*)d_in[19];
    const float* hW1 = (const float*)d_in[20]; const float* hb1  = (const float*)d_in[21];
    const float* hg1 = (const float*)d_in[22]; const float* hbe1 = (const float*)d_in[23];
    const float* hW2 = (const float*)d_in[24]; const float* hb2  = (const float*)d_in[25];
    const float* hg2 = (const float*)d_in[26]; const float* hbe2 = (const float*)d_in[27];
    const float* hW3 = (const float*)d_in[28]; const float* hb3  = (const float*)d_in[29];
    float* out = (float*)d_out;
    (void)n_in; (void)in_sizes;

    char* p = (char*)d_ws;
    size_t off = 0;
    auto alloc = [&](size_t bytes) -> char* {
        char* r = p + off;
        off += (bytes + 255) & ~(size_t)255;
        return r;
    };
    float* h     = (float*)alloc((size_t)NN * HD * 4);
    float* o2    = (float*)alloc((size_t)NN * HD * 4);
    unsigned short* hzd = (unsigned short*)alloc((size_t)NN * 256 * 2);
    unsigned short* hzs = (unsigned short*)alloc((size_t)NN * 256 * 2);
    float* ampv  = (float*)alloc((size_t)NN * 4);
    float* attv  = (float*)alloc((size_t)NN * 4);
    int*   rowptr= (int*)  alloc((size_t)(NN + 1) * 4);
    int*   precs = (int*)  alloc((size_t)NE * 4);
    int*   sc    = (int*)  alloc((size_t)NN * 4);
    int*   stot  = (int*)  alloc((size_t)SCB * 4);
    int*   soff  = (int*)  alloc((size_t)SCB * 4);
    float* cW    = (float*)alloc((size_t)3 * 128 * 256 * 4);
    float* tbb   = (float*)alloc((size_t)3 * 256 * 4);
    unsigned short* bcomb = (unsigned short*)alloc((size_t)3 * 512 * 256 * 2);
    unsigned short* pkPostHi = (unsigned short*)alloc((size_t)3 * 2 * 106496 * 2);
    unsigned short* pkPostLo = (unsigned short*)alloc((size_t)3 * 2 * 106496 * 2);
    unsigned short* pkLinHi  = (unsigned short*)alloc((size_t)3 * 16384 * 2);
    unsigned short* pkLinLo  = (unsigned short*)alloc((size_t)3 * 16384 * 2);
    unsigned short* pkPreHi  = (unsigned short*)alloc((size_t)3 * 65536 * 2);
    unsigned short* pkPreLo  = (unsigned short*)alloc((size_t)3 * 65536 * 2);
    float* gA    = (float*)alloc((size_t)NG * HD * 4);
    float* gB    = (float*)alloc((size_t)NG * HD * 4);
    char* z0 = p + off;   // ---- zero-init region ----
    int*   cnt   = (int*)  alloc((size_t)NN * 4);
    int*   fill  = (int*)  alloc((size_t)NN * 4);
    float* stats = (float*)alloc((size_t)3 * 256 * 4);
    float* hstats= (float*)alloc((size_t)4 * 256 * 4);
    float* g0    = (float*)alloc((size_t)NG * HD * 4);
    size_t zwords = (size_t)((p + off) - z0) / 4;

    if (off > ws_size) {
        k_fill<<<(out_size + 255) / 256, 256, 0, stream>>>(out, (float)ws_size, out_size);
        return;
    }

    k_zero<<<(int)((zwords + 255) / 256), 256, 0, stream>>>((float*)z0, (int)zwords);
    k_encode_nodes<<<NN / 8, 256, 0, stream>>>(x, atom_emb, h);
    k_count<<<(NE + 255) / 256, 256, 0, stream>>>(ei + NE, cnt);
    k_scanA<<<SCB, 1024, 0, stream>>>(cnt, sc, stot);
    k_scanB<<<1, 64, 0, stream>>>(stot, soff);
    k_scanC<<<SCB, 1024, 0, stream>>>(cnt, sc, soff, rowptr, ampv, attv);
    k_scatter<<<(NE + 255) / 256, 256, 0, stream>>>(ei, eai, rowptr, fill, precs);
    k_fold<<<dim3(129, 3), 256, 0, stream>>>(edge_W, edge_b, pre_W, pre_b, cW, tbb);
    k_bcomb2<<<dim3(512, 3), 256, 0, stream>>>(bond_emb, cW, bcomb);
    k_packall<<<1728, 64, 0, stream>>>(post_W, lin_W, pre_W,
        pkPostHi, pkPostLo, pkLinHi, pkLinLo, pkPreHi, pkPreLo);

    int preBlocks = (NN + 31) / 32;
    for (int l = 0; l < 3; ++l) {
        if (l == 0) {
            k_pre_m<<<preBlocks, 256, 0, stream>>>(h, pkPreHi, pkPreLo, tbb, hzd, hzs);
        } else {
            k_bnpre<<<preBlocks, 256, 0, stream>>>(o2, stats + (l - 1) * 256,
                bn_g + (l - 1) * 128, bn_b + (l - 1) * 128,
                pkPreHi + (size_t)l * 65536, pkPreLo + (size_t)l * 65536,
                tbb + l * 256, h, hzd, hzs);
        }
        k_post<<<NN / 16, 256, 0, stream>>>(h, hzd, hzs, rowptr, precs,
            bcomb + (size_t)l * 512 * 256,
            ampv, attv,
            pkPostHi + (size_t)l * 2 * 106496, pkPostLo + (size_t)l * 2 * 106496,
            post_b + l * 2 * 64,
            pkLinHi + (size_t)l * 16384, pkLinLo + (size_t)l * 16384,
            lin_b + l * 128,
            o2, stats + l * 256);
    }

    k_pool<<<(NN + 63) / 64, 128, 0, stream>>>(o2, stats + 2 * 256,
        bn_g + 2 * 128, bn_b + 2 * 128, batch, g0);

    k_head_gemm<<<NG, 128, 0, stream>>>(g0, mlp_W, mlp_b, gA, hstats, 128, 128);
    k_head_fused<<<NG, 128, 0, stream>>>(gA, hstats, mlp_g, mlp_be,
        mlp_W + 128 * 128, mlp_b + 128, gB, hstats + 256, 128, 128);
    k_head_fused<<<NG, 128, 0, stream>>>(gB, hstats + 256, mlp_g + 128, mlp_be + 128,
        hW1, hb1, gA, hstats + 512, 128, 64);
    k_head_fused<<<NG, 128, 0, stream>>>(gA, hstats + 512, hg1, hbe1,
        hW2, hb2, gB, hstats + 768, 64, 32);
    k_head_fused<<<NG, 128, 0, stream>>>(gB, hstats + 768, hg2, hbe2,
        hW3, hb3, out, (float*)nullptr, 32, 3);
}